// Round 4
// baseline (553.667 us; speedup 1.0000x reference)
//
#include <hip/hip_runtime.h>
#include <hip/hip_bf16.h>

#define GAMMA 0.002f
#define NROWS 8192
#define MROWS 8192
#define DDIM  512

#define BM 256
#define BN 256
#define BK 64
#define KT (DDIM / BK)   // 8 k-tiles

// DIAGNOSTIC ROUND: run the K-loop twice (identical result; acc re-zeroed per
// pass) so the GEMM dispatch exceeds the ~210us harness fills and becomes the
// top-1 rocprof dispatch -> first-ever counter visibility for this kernel.
#define KREP 2

typedef __attribute__((ext_vector_type(8))) short bf16x8;
typedef __attribute__((ext_vector_type(4))) float f32x4;
typedef __attribute__((ext_vector_type(8))) unsigned short ushort8;

#define AS1 __attribute__((address_space(1)))
#define AS3 __attribute__((address_space(3)))
#define FENCE asm volatile("" ::: "memory")
#define BARRIER do { FENCE; __builtin_amdgcn_s_barrier(); FENCE; } while (0)
#define VMCNT(n) asm volatile("s_waitcnt vmcnt(" #n ")" ::: "memory")
#define LGKM0    asm volatile("s_waitcnt lgkmcnt(0)" ::: "memory")

static __device__ __forceinline__ unsigned short f32_to_bf16_rne(float f) {
    unsigned int u = __float_as_uint(f);
    unsigned int lsb = (u >> 16) & 1u;
    u += 0x7fffu + lsb;
    return (unsigned short)(u >> 16);
}

// One wave (64 threads) per row: cast fp32 row -> bf16, compute fp32 row norm.
__global__ __launch_bounds__(64) void prep_kernel(const float* __restrict__ src,
                                                  unsigned short* __restrict__ dstb,
                                                  float* __restrict__ sq) {
    const int row  = blockIdx.x;
    const int lane = threadIdx.x;

    const float4* p = (const float4*)(src + (size_t)row * DDIM) + lane * 2;
    float4 f0 = p[0];
    float4 f1 = p[1];

    float s = f0.x*f0.x + f0.y*f0.y + f0.z*f0.z + f0.w*f0.w
            + f1.x*f1.x + f1.y*f1.y + f1.z*f1.z + f1.w*f1.w;

    float t[8] = {f0.x, f0.y, f0.z, f0.w, f1.x, f1.y, f1.z, f1.w};
    ushort8 hv;
#pragma unroll
    for (int i = 0; i < 8; ++i) hv[i] = f32_to_bf16_rne(t[i]);
    *(ushort8*)(dstb + (size_t)row * DDIM + lane * 8) = hv;

#pragma unroll
    for (int off = 32; off > 0; off >>= 1) s += __shfl_down(s, off);
    if (lane == 0) sq[row] = s;
}

// Structure identical to round 3 (4 phases/K-tile, counted vmcnt(4), XOR
// swizzle, setprio), wrapped in KREP passes for profiling visibility.
__global__ __launch_bounds__(512, 2) void rbf_gemm_kernel(
        const unsigned short* __restrict__ xb,
        const unsigned short* __restrict__ yb,
        const float* __restrict__ xsq,
        const float* __restrict__ ysq,
        float* __restrict__ out) {
    // [buf0: A 32K | B 32K][buf1: A 32K | B 32K] = 128 KiB. 128 B rows.
    __shared__ __align__(16) char smem[2 * 65536];
    char* sm = (char*)smem;

    const int tid  = threadIdx.x;
    const int wave = tid >> 6;
    const int lane = tid & 63;

    // Bijective XCD swizzle (1024 blocks, 8 XCDs).
    const int bid = (int)(blockIdx.y * gridDim.x + blockIdx.x);
    const int swz = (bid & 7) * 128 + (bid >> 3);
    const int rowBase = (swz & 31) * BM;
    const int colBase = (swz >> 5) * BN;

    const int wm = wave >> 2;  // 0..1 (row half: 128 rows)
    const int wn = wave & 3;   // 0..3 (col quarter: 64 cols)

    // Fragment read mapping (refcheck-verified):
    const int fr  = lane & 15;
    const int kb0 = ((lane >> 4) << 4) ^ ((lane & 7) << 4);
    const int kb1 = kb0 ^ 64;
    const int aoff = (wm * 128 + fr) * 128;
    const int boff = (wn * 64  + fr) * 128;

    // Cooperative staging: one stg1 across 512 threads = 64 rows x 128 B;
    // LDS dst linear, src byte pre-swizzled: LDS[row][b] = G[row][b^((row&7)<<4)].
    const int srow = tid >> 3;
    const int skb  = (((tid & 7) ^ ((tid >> 3) & 7)) << 4);
    const char* xg = (const char*)xb;
    const char* yg = (const char*)yb;

    auto stg1 = [&](const char* g, int growBase, int kt, int ldsOff) {
        __builtin_amdgcn_global_load_lds(
            (AS1 void*)(g + (size_t)(growBase + srow) * (DDIM * 2) + kt * 128 + skb),
            (AS3 void*)(sm + ldsOff + tid * 16), 16, 0, 0);
    };
    auto stAEV = [&](int kt, int c) {
        stg1(xg, rowBase +   0, kt, c * 65536 +     0);
        stg1(xg, rowBase + 128, kt, c * 65536 + 16384);
    };
    auto stAOD = [&](int kt, int c) {
        stg1(xg, rowBase +  64, kt, c * 65536 +  8192);
        stg1(xg, rowBase + 192, kt, c * 65536 + 24576);
    };
    auto stB1 = [&](int kt, int c) {
        stg1(yg, colBase +   0, kt, c * 65536 + 32768);
        stg1(yg, colBase +  64, kt, c * 65536 + 40960);
    };
    auto stB2 = [&](int kt, int c) {
        stg1(yg, colBase + 128, kt, c * 65536 + 49152);
        stg1(yg, colBase + 192, kt, c * 65536 + 57344);
    };

    auto ldA = [&](const char* smc, int m, int kb) -> bf16x8 {
        return *(const bf16x8*)(smc + aoff + m * 2048 + kb);
    };
    auto ldB = [&](const char* smc, int n, int kb) -> bf16x8 {
        return *(const bf16x8*)(smc + 32768 + boff + n * 2048 + kb);
    };

    f32x4 acc[8][4];

#pragma unroll 1
    for (int rep = 0; rep < KREP; ++rep) {
#pragma unroll
        for (int m = 0; m < 8; ++m)
#pragma unroll
            for (int n = 0; n < 4; ++n) acc[m][n] = (f32x4){0.f, 0.f, 0.f, 0.f};

        // Prologue: tile0 fully + tile1 A-evens (10 loads). vmcnt(4) -> the
        // first 6 (A-ev0,B1_0,B2_0) landed; A-od0 gated at t0.ph0-end.
        stAEV(0, 0); stB1(0, 0); stB2(0, 0); stAOD(0, 0); stAEV(1, 1);
        VMCNT(4);
        BARRIER;

#pragma unroll
        for (int t = 0; t < KT; ++t) {
            const int c = t & 1;
            const char* smc = sm + c * 65536;
            bf16x8 av[4], bv[4];

            // ---- ph0: k0, m0-3 x n0-3 -----------------------------------
            if (t + 1 < KT) stB1(t + 1, c ^ 1);
#pragma unroll
            for (int m = 0; m < 4; ++m) av[m] = ldA(smc, m, kb0);
#pragma unroll
            for (int n = 0; n < 4; ++n) bv[n] = ldB(smc, n, kb0);
            __builtin_amdgcn_s_setprio(1);
#pragma unroll
            for (int m = 0; m < 4; ++m)
#pragma unroll
                for (int n = 0; n < 4; ++n)
                    acc[m][n] = __builtin_amdgcn_mfma_f32_16x16x32_bf16(av[m], bv[n], acc[m][n], 0, 0, 0);
            __builtin_amdgcn_s_setprio(0);
            if (t + 1 < KT) { VMCNT(4); } else { VMCNT(0); }  // frees A-od(t)
            BARRIER;

            // ---- ph1: k0, m4-7 x n0-3 (bv still live) -------------------
            if (t + 1 < KT) stB2(t + 1, c ^ 1);
#pragma unroll
            for (int m = 0; m < 4; ++m) av[m] = ldA(smc, 4 + m, kb0);
            __builtin_amdgcn_s_setprio(1);
#pragma unroll
            for (int m = 0; m < 4; ++m)
#pragma unroll
                for (int n = 0; n < 4; ++n)
                    acc[4 + m][n] = __builtin_amdgcn_mfma_f32_16x16x32_bf16(av[m], bv[n], acc[4 + m][n], 0, 0, 0);
            __builtin_amdgcn_s_setprio(0);
            BARRIER;

            // ---- ph2: k1, m0-3 x n0-3 -----------------------------------
            if (t + 1 < KT) stAOD(t + 1, c ^ 1);
#pragma unroll
            for (int m = 0; m < 4; ++m) av[m] = ldA(smc, m, kb1);
#pragma unroll
            for (int n = 0; n < 4; ++n) bv[n] = ldB(smc, n, kb1);
            __builtin_amdgcn_s_setprio(1);
#pragma unroll
            for (int m = 0; m < 4; ++m)
#pragma unroll
                for (int n = 0; n < 4; ++n)
                    acc[m][n] = __builtin_amdgcn_mfma_f32_16x16x32_bf16(av[m], bv[n], acc[m][n], 0, 0, 0);
            __builtin_amdgcn_s_setprio(0);
            LGKM0;   // ds_reads drained before ph3 overwrites A-ev(buf c)
            BARRIER;

            // ---- ph3: k1, m4-7 x n0-3 -----------------------------------
            if (t + 2 < KT) stAEV(t + 2, c);
#pragma unroll
            for (int m = 0; m < 4; ++m) av[m] = ldA(smc, 4 + m, kb1);
            __builtin_amdgcn_s_setprio(1);
#pragma unroll
            for (int m = 0; m < 4; ++m)
#pragma unroll
                for (int n = 0; n < 4; ++n)
                    acc[4 + m][n] = __builtin_amdgcn_mfma_f32_16x16x32_bf16(av[m], bv[n], acc[4 + m][n], 0, 0, 0);
            __builtin_amdgcn_s_setprio(0);
            if (t + 2 < KT)      { VMCNT(4); }
            else if (t + 1 < KT) { VMCNT(2); }
            LGKM0;   // ds_reads drained before (t+1).ph2 overwrites A-od(c^1)
            if (t + 1 < KT) BARRIER;
        }

        // Rep boundary: drain everything so the next pass's prologue vmcnt
        // arithmetic starts from zero outstanding.
        VMCNT(0);
        BARRIER;
    }

    // Epilogue: C/D layout col = lane&15, row = (lane>>4)*4 + reg  [m89/m91]
    const int q4 = (lane >> 4) * 4;
    const int rb = rowBase + wm * 128;
    const int cb = colBase + wn * 64;
#pragma unroll
    for (int m = 0; m < 8; ++m) {
        float xr[4];
#pragma unroll
        for (int r2 = 0; r2 < 4; ++r2) xr[r2] = xsq[rb + m * 16 + q4 + r2];
#pragma unroll
        for (int n = 0; n < 4; ++n) {
            const int gcol = cb + n * 16 + fr;
            const float ysq_c = ysq[gcol];
#pragma unroll
            for (int r2 = 0; r2 < 4; ++r2) {
                const int grow = rb + m * 16 + q4 + r2;
                float d = xr[r2] + ysq_c - 2.0f * acc[m][n][r2];
                d = fmaxf(d, 0.0f);
                out[(size_t)grow * MROWS + gcol] = __expf(-GAMMA * d);
            }
        }
    }
}

extern "C" void kernel_launch(void* const* d_in, const int* in_sizes, int n_in,
                              void* d_out, int out_size, void* d_ws, size_t ws_size,
                              hipStream_t stream) {
    const float* x = (const float*)d_in[0];
    const float* y = (const float*)d_in[1];
    float* out = (float*)d_out;

    // Workspace layout: xb (8 MiB) | yb (8 MiB) | xsq (32 KiB) | ysq (32 KiB)
    unsigned short* xb = (unsigned short*)d_ws;
    unsigned short* yb = xb + (size_t)NROWS * DDIM;
    float* xsq = (float*)(yb + (size_t)MROWS * DDIM);
    float* ysq = xsq + NROWS;

    prep_kernel<<<NROWS, 64, 0, stream>>>(x, xb, xsq);
    prep_kernel<<<MROWS, 64, 0, stream>>>(y, yb, ysq);

    dim3 grid(NROWS / BM, MROWS / BN);  // 32 x 32 = 1024 blocks
    rbf_gemm_kernel<<<grid, 512, 0, stream>>>(xb, yb, xsq, ysq, out);
}

// Round 5
// 373.599 us; speedup vs baseline: 1.4820x; 1.4820x over previous
//
#include <hip/hip_runtime.h>
#include <hip/hip_bf16.h>

#define GAMMA 0.002f
#define NROWS 8192
#define MROWS 8192
#define DDIM  512

#define BM 256
#define BN 256
#define BK 64
#define KT (DDIM / BK)   // 8 k-tiles

typedef __attribute__((ext_vector_type(8))) short bf16x8;
typedef __attribute__((ext_vector_type(4))) float f32x4;
typedef __attribute__((ext_vector_type(8))) unsigned short ushort8;

#define AS1 __attribute__((address_space(1)))
#define AS3 __attribute__((address_space(3)))
#define FENCE asm volatile("" ::: "memory")
#define BARRIER do { FENCE; __builtin_amdgcn_s_barrier(); FENCE; } while (0)
#define VMCNT(n) asm volatile("s_waitcnt vmcnt(" #n ")" ::: "memory")
#define LGKM0    asm volatile("s_waitcnt lgkmcnt(0)" ::: "memory")

static __device__ __forceinline__ unsigned short f32_to_bf16_rne(float f) {
    unsigned int u = __float_as_uint(f);
    unsigned int lsb = (u >> 16) & 1u;
    u += 0x7fffu + lsb;
    return (unsigned short)(u >> 16);
}

// One wave (64 threads) per row: cast fp32 row -> bf16, compute fp32 row norm.
__global__ __launch_bounds__(64) void prep_kernel(const float* __restrict__ src,
                                                  unsigned short* __restrict__ dstb,
                                                  float* __restrict__ sq) {
    const int row  = blockIdx.x;
    const int lane = threadIdx.x;

    const float4* p = (const float4*)(src + (size_t)row * DDIM) + lane * 2;
    float4 f0 = p[0];
    float4 f1 = p[1];

    float s = f0.x*f0.x + f0.y*f0.y + f0.z*f0.z + f0.w*f0.w
            + f1.x*f1.x + f1.y*f1.y + f1.z*f1.z + f1.w*f1.w;

    float t[8] = {f0.x, f0.y, f0.z, f0.w, f1.x, f1.y, f1.z, f1.w};
    ushort8 hv;
#pragma unroll
    for (int i = 0; i < 8; ++i) hv[i] = f32_to_bf16_rne(t[i]);
    *(ushort8*)(dstb + (size_t)row * DDIM + lane * 8) = hv;

#pragma unroll
    for (int off = 32; off > 0; off >>= 1) s += __shfl_down(s, off);
    if (lane == 0) sq[row] = s;
}

// Structure = round 3 (4 phases/K-tile, counted vmcnt(4), XOR swizzle,
// setprio). NEW vs R4 (counter-driven):
//  - 2D co-residency mapping: R4's FETCH_SIZE showed 15x input re-read
//    (each XCD streamed all 8MB of A through its 4MB L2 every batch).
//    Now each co-resident batch of 32 blocks/XCD covers 8 rowtiles x
//    4 coltiles: working set 3MB < 4MB L2; A fetched once per XCD.
//  - Nontemporal epilogue stores: output (268MB, zero reuse) showed 1.75x
//    write amplification and evicts the K-loop working set from L2.
__global__ __launch_bounds__(512, 2) void rbf_gemm_kernel(
        const unsigned short* __restrict__ xb,
        const unsigned short* __restrict__ yb,
        const float* __restrict__ xsq,
        const float* __restrict__ ysq,
        float* __restrict__ out) {
    // [buf0: A 32K | B 32K][buf1: A 32K | B 32K] = 128 KiB. 128 B rows.
    __shared__ __align__(16) char smem[2 * 65536];
    char* sm = (char*)smem;

    const int tid  = threadIdx.x;
    const int wave = tid >> 6;
    const int lane = tid & 63;

    // --- 2D co-residency mapping (bijective over 1024 tiles) -------------
    // XCD x = bid&7 (dispatch round-robin). Within an XCD, j = bid>>3:
    // batch b = j>>5 (32 co-resident blocks at 1 block/CU), s = j&31.
    // rt = b*8 + (s&7)  (8 A-panels per batch, disjoint across batches)
    // ct = x*4 + (s>>3) (4 B-panels per XCD, resident all pass)
    const int bid = (int)(blockIdx.y * gridDim.x + blockIdx.x);
    const int xcd = bid & 7;
    const int j   = bid >> 3;
    const int b   = j >> 5;
    const int s   = j & 31;
    const int rowBase = (b * 8 + (s & 7)) * BM;
    const int colBase = (xcd * 4 + (s >> 3)) * BN;

    const int wm = wave >> 2;  // 0..1 (row half: 128 rows)
    const int wn = wave & 3;   // 0..3 (col quarter: 64 cols)

    // Fragment read mapping (refcheck-verified):
    const int fr  = lane & 15;
    const int kb0 = ((lane >> 4) << 4) ^ ((lane & 7) << 4);
    const int kb1 = kb0 ^ 64;
    const int aoff = (wm * 128 + fr) * 128;
    const int boff = (wn * 64  + fr) * 128;

    // Cooperative staging: one stg1 across 512 threads = 64 rows x 128 B;
    // LDS dst linear, src pre-swizzled: LDS[row][b] = G[row][b^((row&7)<<4)].
    const int srow = tid >> 3;
    const int skb  = (((tid & 7) ^ ((tid >> 3) & 7)) << 4);
    const char* xg = (const char*)xb;
    const char* yg = (const char*)yb;

    auto stg1 = [&](const char* g, int growBase, int kt, int ldsOff) {
        __builtin_amdgcn_global_load_lds(
            (AS1 void*)(g + (size_t)(growBase + srow) * (DDIM * 2) + kt * 128 + skb),
            (AS3 void*)(sm + ldsOff + tid * 16), 16, 0, 0);
    };
    auto stAEV = [&](int kt, int c) {
        stg1(xg, rowBase +   0, kt, c * 65536 +     0);
        stg1(xg, rowBase + 128, kt, c * 65536 + 16384);
    };
    auto stAOD = [&](int kt, int c) {
        stg1(xg, rowBase +  64, kt, c * 65536 +  8192);
        stg1(xg, rowBase + 192, kt, c * 65536 + 24576);
    };
    auto stB1 = [&](int kt, int c) {
        stg1(yg, colBase +   0, kt, c * 65536 + 32768);
        stg1(yg, colBase +  64, kt, c * 65536 + 40960);
    };
    auto stB2 = [&](int kt, int c) {
        stg1(yg, colBase + 128, kt, c * 65536 + 49152);
        stg1(yg, colBase + 192, kt, c * 65536 + 57344);
    };

    auto ldA = [&](const char* smc, int m, int kb) -> bf16x8 {
        return *(const bf16x8*)(smc + aoff + m * 2048 + kb);
    };
    auto ldB = [&](const char* smc, int n, int kb) -> bf16x8 {
        return *(const bf16x8*)(smc + 32768 + boff + n * 2048 + kb);
    };

    f32x4 acc[8][4];
#pragma unroll
    for (int m = 0; m < 8; ++m)
#pragma unroll
        for (int n = 0; n < 4; ++n) acc[m][n] = (f32x4){0.f, 0.f, 0.f, 0.f};

    // Prologue: tile0 fully + tile1 A-evens (10 loads). vmcnt(4) -> first 6
    // (A-ev0,B1_0,B2_0) landed; A-od0 gated at t0.ph0-end.
    stAEV(0, 0); stB1(0, 0); stB2(0, 0); stAOD(0, 0); stAEV(1, 1);
    VMCNT(4);
    BARRIER;

#pragma unroll
    for (int t = 0; t < KT; ++t) {
        const int c = t & 1;
        const char* smc = sm + c * 65536;
        bf16x8 av[4], bv[4];

        // ---- ph0: k0, m0-3 x n0-3 ---------------------------------------
        if (t + 1 < KT) stB1(t + 1, c ^ 1);
#pragma unroll
        for (int m = 0; m < 4; ++m) av[m] = ldA(smc, m, kb0);
#pragma unroll
        for (int n = 0; n < 4; ++n) bv[n] = ldB(smc, n, kb0);
        __builtin_amdgcn_s_setprio(1);
#pragma unroll
        for (int m = 0; m < 4; ++m)
#pragma unroll
            for (int n = 0; n < 4; ++n)
                acc[m][n] = __builtin_amdgcn_mfma_f32_16x16x32_bf16(av[m], bv[n], acc[m][n], 0, 0, 0);
        __builtin_amdgcn_s_setprio(0);
        if (t + 1 < KT) { VMCNT(4); } else { VMCNT(0); }  // frees A-od(t)
        BARRIER;

        // ---- ph1: k0, m4-7 x n0-3 (bv still live) -----------------------
        if (t + 1 < KT) stB2(t + 1, c ^ 1);
#pragma unroll
        for (int m = 0; m < 4; ++m) av[m] = ldA(smc, 4 + m, kb0);
        __builtin_amdgcn_s_setprio(1);
#pragma unroll
        for (int m = 0; m < 4; ++m)
#pragma unroll
            for (int n = 0; n < 4; ++n)
                acc[4 + m][n] = __builtin_amdgcn_mfma_f32_16x16x32_bf16(av[m], bv[n], acc[4 + m][n], 0, 0, 0);
        __builtin_amdgcn_s_setprio(0);
        BARRIER;

        // ---- ph2: k1, m0-3 x n0-3 ---------------------------------------
        if (t + 1 < KT) stAOD(t + 1, c ^ 1);
#pragma unroll
        for (int m = 0; m < 4; ++m) av[m] = ldA(smc, m, kb1);
#pragma unroll
        for (int n = 0; n < 4; ++n) bv[n] = ldB(smc, n, kb1);
        __builtin_amdgcn_s_setprio(1);
#pragma unroll
        for (int m = 0; m < 4; ++m)
#pragma unroll
            for (int n = 0; n < 4; ++n)
                acc[m][n] = __builtin_amdgcn_mfma_f32_16x16x32_bf16(av[m], bv[n], acc[m][n], 0, 0, 0);
        __builtin_amdgcn_s_setprio(0);
        LGKM0;   // ds_reads drained before ph3 overwrites A-ev(buf c)
        BARRIER;

        // ---- ph3: k1, m4-7 x n0-3 ---------------------------------------
        if (t + 2 < KT) stAEV(t + 2, c);
#pragma unroll
        for (int m = 0; m < 4; ++m) av[m] = ldA(smc, 4 + m, kb1);
        __builtin_amdgcn_s_setprio(1);
#pragma unroll
        for (int m = 0; m < 4; ++m)
#pragma unroll
            for (int n = 0; n < 4; ++n)
                acc[4 + m][n] = __builtin_amdgcn_mfma_f32_16x16x32_bf16(av[m], bv[n], acc[4 + m][n], 0, 0, 0);
        __builtin_amdgcn_s_setprio(0);
        if (t + 2 < KT)      { VMCNT(4); }
        else if (t + 1 < KT) { VMCNT(2); }
        LGKM0;   // ds_reads drained before (t+1).ph2 overwrites A-od(c^1)
        if (t + 1 < KT) BARRIER;
    }

    // Epilogue: C/D layout col = lane&15, row = (lane>>4)*4 + reg  [m89/m91]
    // Nontemporal stores: zero-reuse 268MB stream must not evict L2 panels.
    const int q4 = (lane >> 4) * 4;
    const int rb = rowBase + wm * 128;
    const int cb = colBase + wn * 64;
#pragma unroll
    for (int m = 0; m < 8; ++m) {
        float xr[4];
#pragma unroll
        for (int r2 = 0; r2 < 4; ++r2) xr[r2] = xsq[rb + m * 16 + q4 + r2];
#pragma unroll
        for (int n = 0; n < 4; ++n) {
            const int gcol = cb + n * 16 + fr;
            const float ysq_c = ysq[gcol];
#pragma unroll
            for (int r2 = 0; r2 < 4; ++r2) {
                const int grow = rb + m * 16 + q4 + r2;
                float d = xr[r2] + ysq_c - 2.0f * acc[m][n][r2];
                d = fmaxf(d, 0.0f);
                __builtin_nontemporal_store(__expf(-GAMMA * d),
                                            &out[(size_t)grow * MROWS + gcol]);
            }
        }
    }
}

extern "C" void kernel_launch(void* const* d_in, const int* in_sizes, int n_in,
                              void* d_out, int out_size, void* d_ws, size_t ws_size,
                              hipStream_t stream) {
    const float* x = (const float*)d_in[0];
    const float* y = (const float*)d_in[1];
    float* out = (float*)d_out;

    // Workspace layout: xb (8 MiB) | yb (8 MiB) | xsq (32 KiB) | ysq (32 KiB)
    unsigned short* xb = (unsigned short*)d_ws;
    unsigned short* yb = xb + (size_t)NROWS * DDIM;
    float* xsq = (float*)(yb + (size_t)MROWS * DDIM);
    float* ysq = xsq + NROWS;

    prep_kernel<<<NROWS, 64, 0, stream>>>(x, xb, xsq);
    prep_kernel<<<MROWS, 64, 0, stream>>>(y, yb, ysq);

    dim3 grid(NROWS / BM, MROWS / BN);  // 32 x 32 = 1024 blocks
    rbf_gemm_kernel<<<grid, 512, 0, stream>>>(xb, yb, xsq, ysq, out);
}